// Round 11
// baseline (361.463 us; speedup 1.0000x reference)
//
#include <hip/hip_runtime.h>
#include <cstdint>

typedef float    f32x4 __attribute__((ext_vector_type(4)));
typedef _Float16 f16x8 __attribute__((ext_vector_type(8)));
typedef unsigned int uint32;

// ---------------------------------------------------------------------------
// Workspace (ushort units): two fp16[256][256] arrays (RNE, alpha folded in)
//   [0]      Wn[i][j] = f16(0.5*W[i][j])   (A-operand for Xv update)
//   [65536]  Wt[j][i] = f16(0.5*W[i][j])   (A-operand for Xh update)
// ---------------------------------------------------------------------------

__global__ void HAM_prep_w(const float* __restrict__ W, unsigned short* __restrict__ ws)
{
    int idx = blockIdx.x * 256 + threadIdx.x;          // 0 .. 65535
    int i = idx >> 8, j = idx & 255;
    _Float16 h = (_Float16)(0.5f * W[idx]);            // RNE, rel err <= 2^-12
    unsigned short hb = __builtin_bit_cast(unsigned short, h);
    ws[idx] = hb;
    ws[65536 + j*256 + i] = hb;
}

__device__ __forceinline__ float fast_tanh(float x)
{
    float e = __expf(2.0f * x);
    return 1.0f - __fdividef(2.0f, e + 1.0f);
}

// ---------------------------------------------------------------------------
// 1024 threads = 16 waves; block owns 32 batch rows.
// Waves 0-7: Xv, 32-feature strip each; waves 8-15: Xh likewise.
// W streamed from L2 each iter (allocator refuses 64-reg residency; L2 BW
// ample at ~13 TB/s demand). Latency is hidden by OCCUPANCY:
// amdgpu_waves_per_eu(8) (min 8) caps at 64 VGPRs (round 8 hit 60 naturally)
// -> 8 waves/SIMD = 2 BLOCKS/CU (LDS 2x64 KB = 128 <= 160 KB). Independent
// blocks drift out of phase: one block's MFMA overlaps the other's tanh
// (separate pipes, m114); 8-way TLP hides L2/LDS latency.
// g (fp16) double-buffered in LDS (2 x 32 KiB) -> ONE barrier per iteration.
// Race-free: phase1(it+1) writes buf[(it+1)&1]; stragglers in phase2(it)
// read buf[it&1].
// SWIZZLE ORDER (round-10 NaN lesson): XOR (li<<4) must be applied to the
// FULL pre-swizzle sum. Pre-XOR terms live in disjoint bit fields
// (row*512: bits>=9 | kt*64: bits 6-8 | g*16: bits 4-5), so additions are
// carry-free; XOR (bits 4-7) comes LAST. Never add to an already-XOR'd
// offset: bits 6-7 carry into the row field (that was round 10's NaN).
// ---------------------------------------------------------------------------

__attribute__((amdgpu_waves_per_eu(8)))
__launch_bounds__(1024)
__global__ void HAM_main(const float* __restrict__ xv_in, const float* __restrict__ xh_in,
                         const unsigned short* __restrict__ wsp, const int* __restrict__ miter,
                         float* __restrict__ out)
{
    extern __shared__ char smem[];   // 64 KiB: buf0{gv|gh} buf1{gv|gh}, 16 KiB halves
    const int tid  = threadIdx.x;
    const int wid  = tid >> 6;
    const int lane = tid & 63;
    const int li   = lane & 15;      // MFMA m/n index within tile
    const int g    = lane >> 4;      // quarter-wave group (k-chunk)
    const bool isV = (wid < 8);
    const int fbase = (wid & 7) * 32;
    const long b0 = (long)blockIdx.x * 32;

    const float* xin = isV ? xv_in : xh_in;
    const unsigned short* aP = wsp + (isV ? 0 : 65536);
    const int wrHalf = isV ? 0 : 16384;      // my g goes here (within a buffer)
    const int rdHalf = isV ? 16384 : 0;      // my GEMM consumes the other half
    const int swz = li << 4;                 // XOR swizzle, bits 4-7

    // A-fragment row pointers (ushort units; chunk kt at +kt*32)
    const unsigned short* aRow[2];
    #pragma unroll
    for (int mt = 0; mt < 2; ++mt)
        aRow[mt] = aP + (fbase + mt*16 + li)*256 + g*8;

    // LDS offsets. Writes: fully precomputed (XOR last, nothing added after).
    // Reads: precompute un-XOR'd base; per access (rBase + kt*64) ^ swz.
    int wOff[2][2], rBase[2];
    #pragma unroll
    for (int nt = 0; nt < 2; ++nt) {
        rBase[nt] = (nt*16 + li) * 512 + g*16;
        #pragma unroll
        for (int mt = 0; mt < 2; ++mt)
            wOff[mt][nt] = ((nt*16 + li) * 512 + (fbase + mt*16 + g*4) * 2) ^ swz;
    }

    // ---- load initial state into accumulators (D-layout) ----
    f32x4 acc[2][2];
    #pragma unroll
    for (int mt = 0; mt < 2; ++mt)
        #pragma unroll
        for (int nt = 0; nt < 2; ++nt) {
            long b = b0 + nt*16 + li;
            int  f = fbase + mt*16 + g*4;
            acc[mt][nt] = *(const f32x4*)(xin + b*256 + f);
        }

    const int iters = *miter;

    for (int it = 0; it < iters; ++it) {
        char* buf = smem + (it & 1) * 32768;
        char* wr  = buf + wrHalf;
        char* rd  = buf + rdHalf;

        // ---- phase 1: g = tanh(x) -> fp16 pairs (cvt_pkrtz) -> LDS ----
        #pragma unroll
        for (int mt = 0; mt < 2; ++mt) {
            #pragma unroll
            for (int nt = 0; nt < 2; ++nt) {
                float t0 = fast_tanh(acc[mt][nt][0]);
                float t1 = fast_tanh(acc[mt][nt][1]);
                float t2 = fast_tanh(acc[mt][nt][2]);
                float t3 = fast_tanh(acc[mt][nt][3]);
                uint32 u01 = __builtin_bit_cast(uint32, __builtin_amdgcn_cvt_pkrtz(t0, t1));
                uint32 u23 = __builtin_bit_cast(uint32, __builtin_amdgcn_cvt_pkrtz(t2, t3));
                *(uint2*)(wr + wOff[mt][nt]) = make_uint2(u01, u23);
            }
        }
        __syncthreads();

        // ---- phase 2: x_new = 0.5*x + g_other * (0.5*W) ----
        #pragma unroll
        for (int mt = 0; mt < 2; ++mt)
            #pragma unroll
            for (int nt = 0; nt < 2; ++nt)
                acc[mt][nt] *= 0.5f;

        #pragma unroll
        for (int kt = 0; kt < 8; ++kt) {
            f16x8 a0[2];
            #pragma unroll
            for (int mt = 0; mt < 2; ++mt)
                a0[mt] = *(const f16x8*)(aRow[mt] + kt*32);
            #pragma unroll
            for (int nt = 0; nt < 2; ++nt) {
                // add in disjoint bit-fields FIRST, XOR LAST (carry-free)
                f16x8 bH = *(const f16x8*)(rd + ((rBase[nt] + kt*64) ^ swz));
                #pragma unroll
                for (int mt = 0; mt < 2; ++mt)
                    acc[mt][nt] = __builtin_amdgcn_mfma_f32_16x16x32_f16(a0[mt], bH, acc[mt][nt], 0, 0, 0);
            }
        }
        // no trailing barrier: next phase-1 writes the OTHER buffer
    }

    // ---- epilogue: out[b] = [tanh(xv), tanh(xh)] ----
    const int colBase = (isV ? 0 : 256) + fbase;
    #pragma unroll
    for (int mt = 0; mt < 2; ++mt) {
        #pragma unroll
        for (int nt = 0; nt < 2; ++nt) {
            long b = b0 + nt*16 + li;
            f32x4 o;
            #pragma unroll
            for (int j = 0; j < 4; ++j) o[j] = fast_tanh(acc[mt][nt][j]);
            *(f32x4*)(out + b*512 + colBase + mt*16 + g*4) = o;
        }
    }
}

extern "C" void kernel_launch(void* const* d_in, const int* in_sizes, int n_in,
                              void* d_out, int out_size, void* d_ws, size_t ws_size,
                              hipStream_t stream)
{
    const float* xv   = (const float*)d_in[0];
    const float* xh   = (const float*)d_in[1];
    const float* W    = (const float*)d_in[2];
    const int* miter  = (const int*)d_in[3];
    float* out        = (float*)d_out;
    unsigned short* ws = (unsigned short*)d_ws;

    const int B = in_sizes[0] / 256;        // 32768

    HAM_prep_w<<<256, 256, 0, stream>>>(W, ws);

    (void)hipFuncSetAttribute((const void*)HAM_main,
                              hipFuncAttributeMaxDynamicSharedMemorySize, 65536);
    HAM_main<<<B / 32, 1024, 65536, stream>>>(xv, xh, ws, miter, out);
}

// Round 12
// 359.759 us; speedup vs baseline: 1.0047x; 1.0047x over previous
//
#include <hip/hip_runtime.h>
#include <cstdint>

typedef float    f32x4 __attribute__((ext_vector_type(4)));
typedef _Float16 f16x8 __attribute__((ext_vector_type(8)));
typedef unsigned int uint32;

// ---------------------------------------------------------------------------
// Workspace (ushort units): two fp16[256][256] arrays (RNE, alpha folded in)
//   [0]      Wn[i][j] = f16(0.5*W[i][j])   (A-operand for Xv update)
//   [65536]  Wt[j][i] = f16(0.5*W[i][j])   (A-operand for Xh update)
// ---------------------------------------------------------------------------

__global__ void HAM_prep_w(const float* __restrict__ W, unsigned short* __restrict__ ws)
{
    int idx = blockIdx.x * 256 + threadIdx.x;          // 0 .. 65535
    int i = idx >> 8, j = idx & 255;
    _Float16 h = (_Float16)(0.5f * W[idx]);            // RNE, rel err <= 2^-12
    unsigned short hb = __builtin_bit_cast(unsigned short, h);
    ws[idx] = hb;
    ws[65536 + j*256 + i] = hb;
}

__device__ __forceinline__ float fast_tanh(float x)
{
    float e = __expf(2.0f * x);
    return 1.0f - __fdividef(2.0f, e + 1.0f);
}

// ---------------------------------------------------------------------------
// 1024 threads = 16 waves; block owns 32 batch rows.
// Waves 0-7: Xv, 32-feature strip each; waves 8-15: Xh likewise.
// W streamed from L2 each iter (allocator refuses 64-reg residency; L2 BW
// ample). Latency hidden by OCCUPANCY: __launch_bounds__(1024, 8) declares
// min 8 waves/EU -> VGPR cap 64 (natural demand measured 60 in R8) ->
// 2 BLOCKS/CU (LDS 2x64 KB = 128 <= 160 KB, proven co-resident in R11).
// Independent blocks drift out of phase: one block's MFMA overlaps the
// other's tanh (separate pipes, m114); 8 waves/SIMD hide L2/LDS latency.
// R11 lesson: amdgpu_waves_per_eu(8) min-only drove the allocator to
// VGPR=32 and spilled everything (FETCH 35MB -> 1.08GB). launch_bounds'
// occupancy-target semantics cap at 64 without pathological minimization.
// g (fp16) double-buffered in LDS (2 x 32 KiB) -> ONE barrier per iteration.
// Race-free: phase1(it+1) writes buf[(it+1)&1]; stragglers in phase2(it)
// read buf[it&1].
// SWIZZLE ORDER (round-10 NaN lesson): XOR (li<<4) applied to the FULL
// pre-swizzle sum; pre-XOR terms live in disjoint bit fields (row*512:
// bits>=9 | kt*64: bits 6-8 | g*16: bits 4-5) so additions are carry-free;
// XOR (bits 4-7) comes LAST. Never add to an already-XOR'd offset.
// ---------------------------------------------------------------------------

__launch_bounds__(1024, 8)
__global__ void HAM_main(const float* __restrict__ xv_in, const float* __restrict__ xh_in,
                         const unsigned short* __restrict__ wsp, const int* __restrict__ miter,
                         float* __restrict__ out)
{
    extern __shared__ char smem[];   // 64 KiB: buf0{gv|gh} buf1{gv|gh}, 16 KiB halves
    const int tid  = threadIdx.x;
    const int wid  = tid >> 6;
    const int lane = tid & 63;
    const int li   = lane & 15;      // MFMA m/n index within tile
    const int g    = lane >> 4;      // quarter-wave group (k-chunk)
    const bool isV = (wid < 8);
    const int fbase = (wid & 7) * 32;
    const long b0 = (long)blockIdx.x * 32;

    const float* xin = isV ? xv_in : xh_in;
    const unsigned short* aP = wsp + (isV ? 0 : 65536);
    const int wrHalf = isV ? 0 : 16384;      // my g goes here (within a buffer)
    const int rdHalf = isV ? 16384 : 0;      // my GEMM consumes the other half
    const int swz = li << 4;                 // XOR swizzle, bits 4-7

    // A-fragment row pointers (ushort units; chunk kt at +kt*32)
    const unsigned short* aRow[2];
    #pragma unroll
    for (int mt = 0; mt < 2; ++mt)
        aRow[mt] = aP + (fbase + mt*16 + li)*256 + g*8;

    // LDS offsets. Writes: fully precomputed (XOR last, nothing added after).
    // Reads: precompute un-XOR'd base; per access (rBase + kt*64) ^ swz.
    int wOff[2][2], rBase[2];
    #pragma unroll
    for (int nt = 0; nt < 2; ++nt) {
        rBase[nt] = (nt*16 + li) * 512 + g*16;
        #pragma unroll
        for (int mt = 0; mt < 2; ++mt)
            wOff[mt][nt] = ((nt*16 + li) * 512 + (fbase + mt*16 + g*4) * 2) ^ swz;
    }

    // ---- load initial state into accumulators (D-layout) ----
    f32x4 acc[2][2];
    #pragma unroll
    for (int mt = 0; mt < 2; ++mt)
        #pragma unroll
        for (int nt = 0; nt < 2; ++nt) {
            long b = b0 + nt*16 + li;
            int  f = fbase + mt*16 + g*4;
            acc[mt][nt] = *(const f32x4*)(xin + b*256 + f);
        }

    const int iters = *miter;

    for (int it = 0; it < iters; ++it) {
        char* buf = smem + (it & 1) * 32768;
        char* wr  = buf + wrHalf;
        char* rd  = buf + rdHalf;

        // ---- phase 1: g = tanh(x) -> fp16 pairs (cvt_pkrtz) -> LDS ----
        #pragma unroll
        for (int mt = 0; mt < 2; ++mt) {
            #pragma unroll
            for (int nt = 0; nt < 2; ++nt) {
                float t0 = fast_tanh(acc[mt][nt][0]);
                float t1 = fast_tanh(acc[mt][nt][1]);
                float t2 = fast_tanh(acc[mt][nt][2]);
                float t3 = fast_tanh(acc[mt][nt][3]);
                uint32 u01 = __builtin_bit_cast(uint32, __builtin_amdgcn_cvt_pkrtz(t0, t1));
                uint32 u23 = __builtin_bit_cast(uint32, __builtin_amdgcn_cvt_pkrtz(t2, t3));
                *(uint2*)(wr + wOff[mt][nt]) = make_uint2(u01, u23);
            }
        }
        __syncthreads();

        // ---- phase 2: x_new = 0.5*x + g_other * (0.5*W) ----
        #pragma unroll
        for (int mt = 0; mt < 2; ++mt)
            #pragma unroll
            for (int nt = 0; nt < 2; ++nt)
                acc[mt][nt] *= 0.5f;

        #pragma unroll
        for (int kt = 0; kt < 8; ++kt) {
            f16x8 a0[2];
            #pragma unroll
            for (int mt = 0; mt < 2; ++mt)
                a0[mt] = *(const f16x8*)(aRow[mt] + kt*32);
            #pragma unroll
            for (int nt = 0; nt < 2; ++nt) {
                // add in disjoint bit-fields FIRST, XOR LAST (carry-free)
                f16x8 bH = *(const f16x8*)(rd + ((rBase[nt] + kt*64) ^ swz));
                #pragma unroll
                for (int mt = 0; mt < 2; ++mt)
                    acc[mt][nt] = __builtin_amdgcn_mfma_f32_16x16x32_f16(a0[mt], bH, acc[mt][nt], 0, 0, 0);
            }
        }
        // no trailing barrier: next phase-1 writes the OTHER buffer
    }

    // ---- epilogue: out[b] = [tanh(xv), tanh(xh)] ----
    const int colBase = (isV ? 0 : 256) + fbase;
    #pragma unroll
    for (int mt = 0; mt < 2; ++mt) {
        #pragma unroll
        for (int nt = 0; nt < 2; ++nt) {
            long b = b0 + nt*16 + li;
            f32x4 o;
            #pragma unroll
            for (int j = 0; j < 4; ++j) o[j] = fast_tanh(acc[mt][nt][j]);
            *(f32x4*)(out + b*512 + colBase + mt*16 + g*4) = o;
        }
    }
}

extern "C" void kernel_launch(void* const* d_in, const int* in_sizes, int n_in,
                              void* d_out, int out_size, void* d_ws, size_t ws_size,
                              hipStream_t stream)
{
    const float* xv   = (const float*)d_in[0];
    const float* xh   = (const float*)d_in[1];
    const float* W    = (const float*)d_in[2];
    const int* miter  = (const int*)d_in[3];
    float* out        = (float*)d_out;
    unsigned short* ws = (unsigned short*)d_ws;

    const int B = in_sizes[0] / 256;        // 32768

    HAM_prep_w<<<256, 256, 0, stream>>>(W, ws);

    (void)hipFuncSetAttribute((const void*)HAM_main,
                              hipFuncAttributeMaxDynamicSharedMemorySize, 65536);
    HAM_main<<<B / 32, 1024, 65536, stream>>>(xv, xh, ws, miter, out);
}

// Round 13
// 177.729 us; speedup vs baseline: 2.0338x; 2.0242x over previous
//
#include <hip/hip_runtime.h>
#include <cstdint>

typedef float    f32x4 __attribute__((ext_vector_type(4)));
typedef _Float16 f16x8 __attribute__((ext_vector_type(8)));
typedef unsigned int uint32;

// ---------------------------------------------------------------------------
// Workspace (ushort units): two fp16[256][256] arrays (RNE, alpha folded in)
//   [0]      Wn[i][j] = f16(0.5*W[i][j])   (A-operand for Xv update)
//   [65536]  Wt[j][i] = f16(0.5*W[i][j])   (A-operand for Xh update)
// ---------------------------------------------------------------------------

__global__ void HAM_prep_w(const float* __restrict__ W, unsigned short* __restrict__ ws)
{
    int idx = blockIdx.x * 256 + threadIdx.x;          // 0 .. 65535
    int i = idx >> 8, j = idx & 255;
    _Float16 h = (_Float16)(0.5f * W[idx]);            // RNE, rel err <= 2^-12
    unsigned short hb = __builtin_bit_cast(unsigned short, h);
    ws[idx] = hb;
    ws[65536 + j*256 + i] = hb;
}

__device__ __forceinline__ float fast_tanh(float x)
{
    float e = __expf(2.0f * x);
    return 1.0f - __fdividef(2.0f, e + 1.0f);
}

// ---------------------------------------------------------------------------
// R13: 512 threads = 8 waves; block owns 32 batch rows; 1024 blocks.
// Waves 0-3: Xv, 64-feat strips; waves 4-7: Xh likewise. W streamed from L2.
// GOAL: 2+ blocks/CU co-resident and drifting out of phase, so one block's
// tanh (VALU) overlaps the other's MFMA (separate pipes, m114).
// Ledger: any 8-waves/EU register target (cap 64) -> backend collapses to
// VGPR=32 + spills (R11/R12). So: NATURAL allocation (~104 VGPR <= 128 ->
// 4 waves/SIMD -> 16 waves = 2 blocks fit), and LDS shrunk to 32 KB/block
// (single g buffer, TWO barriers/iter) so up to 4 blocks fit by LDS.
// No waves_per_eu, no min-occupancy bound: let the scheduler pack.
// Swizzle (R10 lesson): XOR (li<<4) applied LAST to the full sum; pre-XOR
// terms live in disjoint bit fields (row*512 >=9 | kt*64 6-8 | g*16 4-5).
// Race safety: single buffer needs barrier AFTER phase2 too (write-after-
// read), giving the 2-barrier iteration:
//   phase1 write own g | bar | phase2 MFMA reads other g | bar | next iter
// ---------------------------------------------------------------------------

__launch_bounds__(512)
__global__ void HAM_main(const float* __restrict__ xv_in, const float* __restrict__ xh_in,
                         const unsigned short* __restrict__ wsp, const int* __restrict__ miter,
                         float* __restrict__ out)
{
    extern __shared__ char smem[];   // 32 KiB: gv[32][256] | gh[32][256], fp16
    const int tid  = threadIdx.x;
    const int wid  = tid >> 6;
    const int lane = tid & 63;
    const int li   = lane & 15;      // MFMA m/n index within tile
    const int g    = lane >> 4;      // quarter-wave group (k-chunk)
    const bool isV = (wid < 4);
    const int fbase = (wid & 3) * 64;
    const long b0 = (long)blockIdx.x * 32;

    const float* xin = isV ? xv_in : xh_in;
    const unsigned short* aP = wsp + (isV ? 0 : 65536);
    char* wr = smem + (isV ? 0 : 16384);     // my g goes here
    char* rd = smem + (isV ? 16384 : 0);     // my GEMM consumes the other half
    const int swz = li << 4;                 // XOR swizzle, bits 4-7

    // A-fragment row pointers (ushort units; chunk kt at +kt*32)
    const unsigned short* aRow[4];
    #pragma unroll
    for (int mt = 0; mt < 4; ++mt)
        aRow[mt] = aP + (fbase + mt*16 + li)*256 + g*8;

    // LDS offsets. Writes: fully precomputed (XOR last, nothing added after).
    // Reads: un-XOR'd base; per access (rBase + kt*64) ^ swz (disjoint fields).
    int wOff[4][2], rBase[2];
    #pragma unroll
    for (int nt = 0; nt < 2; ++nt) {
        rBase[nt] = (nt*16 + li) * 512 + g*16;
        #pragma unroll
        for (int mt = 0; mt < 4; ++mt)
            wOff[mt][nt] = ((nt*16 + li) * 512 + (fbase + mt*16 + g*4) * 2) ^ swz;
    }

    // ---- load initial state into accumulators (D-layout) ----
    f32x4 acc[4][2];
    #pragma unroll
    for (int mt = 0; mt < 4; ++mt)
        #pragma unroll
        for (int nt = 0; nt < 2; ++nt) {
            long b = b0 + nt*16 + li;
            int  f = fbase + mt*16 + g*4;
            acc[mt][nt] = *(const f32x4*)(xin + b*256 + f);
        }

    const int iters = *miter;

    for (int it = 0; it < iters; ++it) {
        // ---- phase 1: g = tanh(x) -> fp16 pairs (cvt_pkrtz) -> LDS ----
        #pragma unroll
        for (int mt = 0; mt < 4; ++mt) {
            #pragma unroll
            for (int nt = 0; nt < 2; ++nt) {
                float t0 = fast_tanh(acc[mt][nt][0]);
                float t1 = fast_tanh(acc[mt][nt][1]);
                float t2 = fast_tanh(acc[mt][nt][2]);
                float t3 = fast_tanh(acc[mt][nt][3]);
                uint32 u01 = __builtin_bit_cast(uint32, __builtin_amdgcn_cvt_pkrtz(t0, t1));
                uint32 u23 = __builtin_bit_cast(uint32, __builtin_amdgcn_cvt_pkrtz(t2, t3));
                *(uint2*)(wr + wOff[mt][nt]) = make_uint2(u01, u23);
            }
        }
        __syncthreads();

        // ---- phase 2: x_new = 0.5*x + g_other * (0.5*W) ----
        #pragma unroll
        for (int mt = 0; mt < 4; ++mt)
            #pragma unroll
            for (int nt = 0; nt < 2; ++nt)
                acc[mt][nt] *= 0.5f;

        #pragma unroll
        for (int kt = 0; kt < 8; ++kt) {
            f16x8 a0[4];
            #pragma unroll
            for (int mt = 0; mt < 4; ++mt)
                a0[mt] = *(const f16x8*)(aRow[mt] + kt*32);
            #pragma unroll
            for (int nt = 0; nt < 2; ++nt) {
                // add in disjoint bit-fields FIRST, XOR LAST (carry-free)
                f16x8 bH = *(const f16x8*)(rd + ((rBase[nt] + kt*64) ^ swz));
                #pragma unroll
                for (int mt = 0; mt < 4; ++mt)
                    acc[mt][nt] = __builtin_amdgcn_mfma_f32_16x16x32_f16(a0[mt], bH, acc[mt][nt], 0, 0, 0);
            }
        }
        __syncthreads();   // write-after-read guard for the single g buffer
    }

    // ---- epilogue: out[b] = [tanh(xv), tanh(xh)] ----
    const int colBase = (isV ? 0 : 256) + fbase;
    #pragma unroll
    for (int mt = 0; mt < 4; ++mt) {
        #pragma unroll
        for (int nt = 0; nt < 2; ++nt) {
            long b = b0 + nt*16 + li;
            f32x4 o;
            #pragma unroll
            for (int j = 0; j < 4; ++j) o[j] = fast_tanh(acc[mt][nt][j]);
            *(f32x4*)(out + b*512 + colBase + mt*16 + g*4) = o;
        }
    }
}

extern "C" void kernel_launch(void* const* d_in, const int* in_sizes, int n_in,
                              void* d_out, int out_size, void* d_ws, size_t ws_size,
                              hipStream_t stream)
{
    const float* xv   = (const float*)d_in[0];
    const float* xh   = (const float*)d_in[1];
    const float* W    = (const float*)d_in[2];
    const int* miter  = (const int*)d_in[3];
    float* out        = (float*)d_out;
    unsigned short* ws = (unsigned short*)d_ws;

    const int B = in_sizes[0] / 256;        // 32768

    HAM_prep_w<<<256, 256, 0, stream>>>(W, ws);

    HAM_main<<<B / 32, 512, 32768, stream>>>(xv, xh, ws, miter, out);
}